// Round 18
// baseline (377.150 us; speedup 1.0000x reference)
//
#include <hip/hip_runtime.h>
#include <hip/hip_bf16.h>
#include <stdint.h>

#define B_ 8
#define N_ 1025
#define C_ 1024
#define H_ 8
#define D_ 128
#define TOK_ 1024
#define LORA_ 16
#define M_ 8200          // B_*N_
#define NPAD_ 1032       // padded N for vvT rows

using bf16x8 = __attribute__((ext_vector_type(8))) short;
using f32x4  = __attribute__((ext_vector_type(4))) float;
typedef unsigned short u16;

__device__ __forceinline__ u16 f2bf(float f) {
    union { float f; unsigned u; } v; v.f = f;
    unsigned r = v.u + 0x7fffu + ((v.u >> 16) & 1u);   // RNE
    return (u16)(r >> 16);
}
__device__ __forceinline__ float bf2f(short h) {
    union { unsigned u; float f; } v; v.u = ((unsigned)(unsigned short)h) << 16; return v.f;
}

__device__ __forceinline__ unsigned cvt_pk_bf16(float lo, float hi) {
    unsigned r;
    asm("v_cvt_pk_bf16_f32 %0, %1, %2" : "=v"(r) : "v"(lo), "v"(hi));
    return r;
}

__device__ __forceinline__ void gload16(const u16* g, u16* l) {
    __builtin_amdgcn_global_load_lds(
        (const __attribute__((address_space(1))) void*)g,
        (__attribute__((address_space(3))) void*)l, 16, 0, 0);
}

// bijective XCD swizzle (nwg % 8 == 0)
__device__ __forceinline__ int xcd_swz(int bid, int nwg) {
    int cpx = nwg >> 3;
    return (bid & 7) * cpx + (bid >> 3);
}
// general bijective XCD swizzle (m204 form, any nwg)
__device__ __forceinline__ int xcd_swz_g(int bid, int nwg) {
    int q = nwg >> 3, r = nwg & 7;
    int xcd = bid & 7, i = bid >> 3;
    return (xcd < r ? xcd * (q + 1) : r * (q + 1) + (xcd - r) * q) + i;
}

// ---------------- fp32 -> bf16 cast (x, style_k, style_v), 8 elems/thread --------------
__global__ __launch_bounds__(256) void cast3_kernel(
    const float* __restrict__ x, const float* __restrict__ sk, const float* __restrict__ sv,
    u16* __restrict__ xb, u16* __restrict__ skb, u16* __restrict__ svb)
{
    const float* in = blockIdx.y == 0 ? x : (blockIdx.y == 1 ? sk : sv);
    u16* out = blockIdx.y == 0 ? xb : (blockIdx.y == 1 ? skb : svb);
    size_t i = (size_t)blockIdx.x * 256 + threadIdx.x;   // covers M_*C_/8 exactly
    float4 a = *((const float4*)in + i * 2);
    float4 b = *((const float4*)in + i * 2 + 1);
    bf16x8 v;
    v[0] = (short)f2bf(a.x); v[1] = (short)f2bf(a.y);
    v[2] = (short)f2bf(a.z); v[3] = (short)f2bf(a.w);
    v[4] = (short)f2bf(b.x); v[5] = (short)f2bf(b.y);
    v[6] = (short)f2bf(b.z); v[7] = (short)f2bf(b.w);
    *(bf16x8*)(out + i * 8) = v;
}

// ---------------- ak/av (1024x16 f32) -> padded bf16 (1024x32, hi 16 cols = 0) ---------
__global__ __launch_bounds__(256) void padcast16_kernel(
    const float* __restrict__ ak, const float* __restrict__ av,
    u16* __restrict__ akp, u16* __restrict__ avp)
{
    const float* in = blockIdx.y ? av : ak;
    u16* out = blockIdx.y ? avp : akp;
    int i = blockIdx.x * 256 + threadIdx.x;          // over 1024*16
    int t = i >> 4, l = i & 15;
    out[(size_t)t * 32 + l] = f2bf(in[i]);
    out[(size_t)t * 32 + 16 + l] = 0;
}

// ---------------- bk/bv (16x1024 f32) -> bf16 ------------------------------------------
__global__ __launch_bounds__(256) void castb_kernel(
    const float* __restrict__ bk, const float* __restrict__ bv,
    u16* __restrict__ bkb, u16* __restrict__ bvb)
{
    const float* in = blockIdx.y ? bv : bk;
    u16* out = blockIdx.y ? bvb : bkb;
    int i = blockIdx.x * 256 + threadIdx.x;          // over 16*1024
    out[i] = f2bf(in[i]);
}

// ---------------- rank-16 projection via MFMA: op[m][l] = sum_c sb[m][c]*bb[l][c] ------
__global__ __launch_bounds__(256) void lora16_mfma(
    const u16* __restrict__ skb, const u16* __restrict__ svb,
    const u16* __restrict__ bkb, const u16* __restrict__ bvb,
    u16* __restrict__ sk16p, u16* __restrict__ sv16p)
{
    const u16* sb = blockIdx.y ? svb : skb;
    const u16* bb = blockIdx.y ? bvb : bkb;
    u16* op = blockIdx.y ? sv16p : sk16p;
    const int lane = threadIdx.x & 63, wid = threadIdx.x >> 6;
    const int base = blockIdx.x * 64 + wid * 16;
    int ma = base + (lane & 15); if (ma > M_ - 1) ma = M_ - 1;
    const int l = lane & 15;
    const u16* arow = sb + (size_t)ma * C_ + (lane >> 4) * 8;
    const u16* brow = bb + (size_t)l * C_ + (lane >> 4) * 8;
    f32x4 acc = {0.f, 0.f, 0.f, 0.f};
#pragma unroll
    for (int k0 = 0; k0 < C_; k0 += 32) {
        bf16x8 af = *(const bf16x8*)(arow + k0);
        bf16x8 bf = *(const bf16x8*)(brow + k0);
        acc = __builtin_amdgcn_mfma_f32_16x16x32_bf16(af, bf, acc, 0, 0, 0);
    }
#pragma unroll
    for (int r = 0; r < 4; ++r) {
        int m = base + (lane >> 4) * 4 + r; if (m > M_ - 1) m = M_ - 1;
        op[(size_t)m * 32 + l] = f2bf(acc[r]);
        op[(size_t)m * 32 + 16 + l] = 0;
    }
}

// ---------------- weight transpose+cast: in (K x Nw) f32 -> out (Nw x K) bf16 ----------
__global__ __launch_bounds__(256) void wt_kernel(
    const float* __restrict__ in, u16* __restrict__ out, int K, int Nw)
{
    __shared__ float t[32][33];
    int n0 = blockIdx.x * 32, k0 = blockIdx.y * 32;
    int tx = threadIdx.x & 31, ty = threadIdx.x >> 5;
#pragma unroll
    for (int yy = 0; yy < 32; yy += 8)
        t[ty + yy][tx] = in[(size_t)(k0 + ty + yy) * Nw + n0 + tx];
    __syncthreads();
#pragma unroll
    for (int yy = 0; yy < 32; yy += 8)
        out[(size_t)(n0 + ty + yy) * K + k0 + tx] = f2bf(t[tx][ty + yy]);
}

// ---------------- x[b,1+t,c] f32 -> xT bf16 [b*1024+c][t] ------------------------------
__global__ __launch_bounds__(256) void xt_kernel(
    const float* __restrict__ x, u16* __restrict__ xT)
{
    __shared__ float tb[32][33];
    int t0 = blockIdx.x * 32, c0 = blockIdx.y * 32, b = blockIdx.z;
    int tx = threadIdx.x & 31, ty = threadIdx.x >> 5;
#pragma unroll
    for (int yy = 0; yy < 32; yy += 8)
        tb[ty + yy][tx] = x[((size_t)b * N_ + 1 + t0 + ty + yy) * C_ + c0 + tx];
    __syncthreads();
#pragma unroll
    for (int yy = 0; yy < 32; yy += 8)
        xT[((size_t)b * 1024 + c0 + ty + yy) * 1024 + t0 + tx] = f2bf(tb[tx][ty + yy]);
}

// ---------------- vv (f32) -> vvT bf16 [bh*128+d][NPAD_] -------------------------------
__global__ __launch_bounds__(256) void vvt_kernel(
    const float* __restrict__ vv, u16* __restrict__ vvT)
{
    __shared__ float t[32][33];
    int n0 = blockIdx.x * 32, d0 = blockIdx.y * 32, bh = blockIdx.z;
    int b = bh >> 3, h = bh & 7;
    int tx = threadIdx.x & 31, ty = threadIdx.x >> 5;
#pragma unroll
    for (int yy = 0; yy < 32; yy += 8) {
        int n = n0 + ty + yy; if (n > 1024) n = 1024;
        t[ty + yy][tx] = vv[((size_t)(b * N_) + n) * C_ + h * D_ + d0 + tx];
    }
    __syncthreads();
#pragma unroll
    for (int yy = 0; yy < 32; yy += 8) {
        int n = n0 + tx;
        if (n < NPAD_)
            vvT[((size_t)bh * D_ + d0 + ty + yy) * NPAD_ + n] = f2bf(t[tx][ty + yy]);
    }
}

// ---------------- MFMA GEMM core, 256-thr 128x128 (kept for se_gemm) -------------------
__device__ __forceinline__ void stage_tile(
    const u16* __restrict__ base, int row0, int maxrow,
    u16* lds, int k0, int lane, int wid)
{
#pragma unroll
    for (int j = 0; j < 4; ++j) {
        int i = wid * 4 + j;
        int p = i * 1024 + 16 * lane;
        int row = p >> 7, cb = p & 127;
        int cbs = cb ^ ((row & 7) << 4);
        int gr = row0 + row; if (gr > maxrow) gr = maxrow;
        gload16(base + (size_t)gr * 1024 + k0 + (cbs >> 1), lds + i * 512);
    }
}

__device__ __forceinline__ void gemm_pass(
    const u16* __restrict__ A, const u16* __restrict__ Bt, int row0, int nb0,
    u16* As, u16* Bs, f32x4 acc[4][4],
    const int lane, const int wid, const int wr, const int wc)
{
    for (int k0 = 0; k0 < 1024; k0 += 64) {
        __syncthreads();
        stage_tile(A,  row0, M_ - 1,    As, k0, lane, wid);
        stage_tile(Bt, nb0,  (1 << 30), Bs, k0, lane, wid);
        __syncthreads();
#pragma unroll
        for (int ks = 0; ks < 2; ++ks) {
            bf16x8 af[4], bfr[4];
#pragma unroll
            for (int mi = 0; mi < 4; ++mi) {
                int r = wr * 64 + mi * 16 + (lane & 15);
                int byte = (r * 128 + ks * 64 + (lane >> 4) * 16) ^ ((r & 7) << 4);
                af[mi] = *(const bf16x8*)((const char*)As + byte);
            }
#pragma unroll
            for (int ni = 0; ni < 4; ++ni) {
                int r = wc * 64 + ni * 16 + (lane & 15);
                int byte = (r * 128 + ks * 64 + (lane >> 4) * 16) ^ ((r & 7) << 4);
                bfr[ni] = *(const bf16x8*)((const char*)Bs + byte);
            }
#pragma unroll
            for (int mi = 0; mi < 4; ++mi)
#pragma unroll
                for (int ni = 0; ni < 4; ++ni)
                    acc[mi][ni] = __builtin_amdgcn_mfma_f32_16x16x32_bf16(
                        af[mi], bfr[ni], acc[mi][ni], 0, 0, 0);
        }
    }
}

// ---------------- MFMA GEMM core, 512-thr 128x256 (halved A-refetch) -------------------
template<int NSEG>
__device__ __forceinline__ void stage_tile512(
    const u16* __restrict__ base, int row0, int maxrow,
    u16* lds, int k0, int lane, int wid)
{
#pragma unroll
    for (int j = 0; j < NSEG; ++j) {
        int i = wid * NSEG + j;
        int p = i * 1024 + 16 * lane;
        int row = p >> 7, cb = p & 127;
        int cbs = cb ^ ((row & 7) << 4);
        int gr = row0 + row; if (gr > maxrow) gr = maxrow;
        gload16(base + (size_t)gr * 1024 + k0 + (cbs >> 1), lds + i * 512);
    }
}

__device__ __forceinline__ void gemm_pass512(
    const u16* __restrict__ A, const u16* __restrict__ Bt, int row0, int nb0,
    u16* As, u16* Bs, f32x4 acc[4][4],
    const int lane, const int wid, const int wr, const int wc)
{
    for (int k0 = 0; k0 < 1024; k0 += 64) {
        __syncthreads();
        stage_tile512<2>(A,  row0, M_ - 1,    As, k0, lane, wid);   // 128 rows
        stage_tile512<4>(Bt, nb0,  (1 << 30), Bs, k0, lane, wid);   // 256 rows
        __syncthreads();
#pragma unroll
        for (int ks = 0; ks < 2; ++ks) {
            bf16x8 af[4], bfr[4];
#pragma unroll
            for (int mi = 0; mi < 4; ++mi) {
                int r = wr * 64 + mi * 16 + (lane & 15);
                int byte = (r * 128 + ks * 64 + (lane >> 4) * 16) ^ ((r & 7) << 4);
                af[mi] = *(const bf16x8*)((const char*)As + byte);
            }
#pragma unroll
            for (int ni = 0; ni < 4; ++ni) {
                int r = wc * 64 + ni * 16 + (lane & 15);
                int byte = (r * 128 + ks * 64 + (lane >> 4) * 16) ^ ((r & 7) << 4);
                bfr[ni] = *(const bf16x8*)((const char*)Bs + byte);
            }
#pragma unroll
            for (int mi = 0; mi < 4; ++mi)
#pragma unroll
                for (int ni = 0; ni < 4; ++ni)
                    acc[mi][ni] = __builtin_amdgcn_mfma_f32_16x16x32_bf16(
                        af[mi], bfr[ni], acc[mi][ni], 0, 0, 0);
        }
    }
}

// ---------------- SE module: one j-pass per block, global partials ---------------------
__global__ __launch_bounds__(256) void se_gemm(
    const u16* __restrict__ xT, const u16* __restrict__ W1T,
    const float* __restrict__ b1, const float* __restrict__ W2,
    float* __restrict__ gred)
{
    __shared__ u16 As[8192], Bs[8192];
    __shared__ float red[128];
    const int tid = threadIdx.x, lane = tid & 63, wid = tid >> 6;
    const int wr = wid >> 1, wc = wid & 1;
    const int row0 = blockIdx.x * 128;
    const int pass = blockIdx.y;
    if (tid < 128) red[tid] = 0.f;
    const f32x4 FZ = {0.f, 0.f, 0.f, 0.f};

    f32x4 acc[4][4];
#pragma unroll
    for (int mi = 0; mi < 4; ++mi)
#pragma unroll
        for (int ni = 0; ni < 4; ++ni) acc[mi][ni] = FZ;
    gemm_pass(xT, W1T, row0, pass * 128, As, Bs, acc, lane, wid, wr, wc);
#pragma unroll
    for (int mi = 0; mi < 4; ++mi) {
#pragma unroll
        for (int r = 0; r < 4; ++r) {
            float v = 0.f;
#pragma unroll
            for (int ni = 0; ni < 4; ++ni) {
                int j = pass * 128 + wc * 64 + ni * 16 + (lane & 15);
                float h = acc[mi][ni][r] + b1[j];
                v += fmaxf(h, 0.f) * W2[j];
            }
#pragma unroll
            for (int off = 1; off < 16; off <<= 1) v += __shfl_xor(v, off);
            if ((lane & 15) == 0)
                atomicAdd(&red[wr * 64 + mi * 16 + (lane >> 4) * 4 + r], v);
        }
    }
    __syncthreads();
    if (tid < 128) atomicAdd(&gred[row0 + tid], red[tid]);
}

__global__ __launch_bounds__(256) void se_fin(
    const float* __restrict__ gred, const float* __restrict__ b2,
    const float* __restrict__ x, float* __restrict__ wcls)
{
    int row = blockIdx.x * 256 + threadIdx.x;    // 8192 rows
    int b = row >> 10, c = row & 1023;
    wcls[row] = x[(size_t)b * N_ * C_ + c] / (1.f + expf(-(gred[row] + b2[0])));
}

// ---------------- fused qkv GEMM (512 thr, 128x256): q / kk / vv + rank-16 LoRA --------
__global__ __launch_bounds__(512) void qkv_gemm(
    const u16* __restrict__ xb, const u16* __restrict__ WqkvT,
    const u16* __restrict__ sk16p, const u16* __restrict__ sv16p,
    const u16* __restrict__ akp, const u16* __restrict__ avp,
    u16* __restrict__ qb, u16* __restrict__ kkb, float* __restrict__ vvout)
{
    __shared__ u16 As[8192], Bs[16384];
    const int tid = threadIdx.x, lane = tid & 63, wid = tid >> 6;
    const int wr = wid >> 2, wc = wid & 3;
    const int swz = xcd_swz_g(blockIdx.x, 65 * 12);
    const int row0 = (swz / 12) * 128;          // A-locality: ct fastest
    const int ct = swz % 12, region = ct >> 2;
    const int creg = (ct & 3) * 256;            // column base within region
    const f32x4 FZ = {0.f, 0.f, 0.f, 0.f};
    f32x4 acc[4][4];
#pragma unroll
    for (int mi = 0; mi < 4; ++mi)
#pragma unroll
        for (int ni = 0; ni < 4; ++ni) acc[mi][ni] = FZ;

    gemm_pass512(xb, WqkvT, row0, region * 1024 + creg, As, Bs, acc, lane, wid, wr, wc);

    if (region >= 1) {
        const u16* a16 = (region == 1) ? sk16p : sv16p;
        const u16* b16 = (region == 1) ? akp : avp;
        bf16x8 af2[4], bf2v[4];
#pragma unroll
        for (int mi = 0; mi < 4; ++mi) {
            int gr = row0 + wr * 64 + mi * 16 + (lane & 15);
            if (gr > M_ - 1) gr = M_ - 1;
            af2[mi] = *(const bf16x8*)(a16 + (size_t)gr * 32 + (lane >> 4) * 8);
        }
#pragma unroll
        for (int ni = 0; ni < 4; ++ni) {
            int gc = creg + wc * 64 + ni * 16 + (lane & 15);
            bf2v[ni] = *(const bf16x8*)(b16 + (size_t)gc * 32 + (lane >> 4) * 8);
        }
#pragma unroll
        for (int mi = 0; mi < 4; ++mi)
#pragma unroll
            for (int ni = 0; ni < 4; ++ni)
                acc[mi][ni] = __builtin_amdgcn_mfma_f32_16x16x32_bf16(
                    af2[mi], bf2v[ni], acc[mi][ni], 0, 0, 0);
    }

    const float QSCALE = 0.1275006182f;   // (1/sqrt(128))*log2(e), folded into q
#pragma unroll
    for (int mi = 0; mi < 4; ++mi) {
#pragma unroll
        for (int r = 0; r < 4; ++r) {
            int gr = row0 + wr * 64 + mi * 16 + (lane >> 4) * 4 + r;
            if (gr >= M_) continue;
#pragma unroll
            for (int ni = 0; ni < 4; ++ni) {
                int gc = creg + wc * 64 + ni * 16 + (lane & 15);
                float v = acc[mi][ni][r];
                if (region == 0)      qb [(size_t)gr * C_ + gc] = f2bf(v * QSCALE);
                else if (region == 1) kkb[(size_t)gr * C_ + gc] = f2bf(v);
                else                  vvout[(size_t)gr * C_ + gc] = v;
            }
        }
    }
}

// ---------------- proj GEMM (512 thr, 128x256) -----------------------------------------
__global__ __launch_bounds__(512) void proj_gemm(
    const u16* __restrict__ ob, const u16* __restrict__ WprojT,
    const float* __restrict__ bias, const float* __restrict__ wcls,
    float* __restrict__ outp)
{
    __shared__ u16 As[8192], Bs[16384];
    const int tid = threadIdx.x, lane = tid & 63, wid = tid >> 6;
    const int wr = wid >> 2, wc = wid & 3;
    const int swz = xcd_swz_g(blockIdx.x, 65 * 4);
    const int row0 = (swz / 4) * 128;
    const int ct = swz % 4;
    const f32x4 FZ = {0.f, 0.f, 0.f, 0.f};
    f32x4 acc[4][4];
#pragma unroll
    for (int mi = 0; mi < 4; ++mi)
#pragma unroll
        for (int ni = 0; ni < 4; ++ni) acc[mi][ni] = FZ;

    gemm_pass512(ob, WprojT, row0, ct * 256, As, Bs, acc, lane, wid, wr, wc);

#pragma unroll
    for (int mi = 0; mi < 4; ++mi) {
#pragma unroll
        for (int r = 0; r < 4; ++r) {
            int gr = row0 + wr * 64 + mi * 16 + (lane >> 4) * 4 + r;
            if (gr >= M_) continue;
#pragma unroll
            for (int ni = 0; ni < 4; ++ni) {
                int gc = ct * 256 + wc * 64 + ni * 16 + (lane & 15);
                float v = acc[mi][ni][r] + bias[gc];
                if (gr % N_ == 0) v += wcls[(gr / N_) * C_ + gc];
                outp[(size_t)gr * C_ + gc] = v;
            }
        }
    }
}

// ---------------- flash attention main: rows 0..1023, grid 16x64 = 1024 (no tail) ------
__device__ __forceinline__ int psw(int pr, int colb) {
    return (pr * 128 + colb) ^ ((pr & 7) << 4) ^ ((pr & 8) << 2);
}

__global__ __launch_bounds__(256) void attn_kernel(
    const u16* __restrict__ qb, const u16* __restrict__ kkb,
    const u16* __restrict__ vvT, u16* __restrict__ ob)
{
    __shared__ u16 Ks[8192];   // 16 KB
    __shared__ u16 Vs[8192];   // 16 KB
    __shared__ u16 Ps[4096];   // 8 KB  (per-wave 2KB, wave-private)
    const int tid = threadIdx.x, lane = tid & 63, wid = tid >> 6;
    const int swz = xcd_swz(blockIdx.x, 16 * 64);
    const int qt = swz % 16, bh = swz / 16, b = bh >> 3, h = bh & 7;
    const int n0q = qt * 64;
    const float THR = 11.54f;         // 8 nats in bits (scores already log2-scaled via q)
    const u16* kbase = kkb + (size_t)b * N_ * C_ + h * D_;
    const u16* vbase = vvT + (size_t)bh * D_ * NPAD_;

    bf16x8 qf[4];
    {
        int qrow = n0q + wid * 16 + (lane & 15);            // <= 1023 always
        const u16* qbase = qb + (size_t)(b * N_ + qrow) * C_ + h * D_ + (lane >> 4) * 8;
#pragma unroll
        for (int ks = 0; ks < 4; ++ks) qf[ks] = *(const bf16x8*)(qbase + ks * 32);
    }

    // staging base pointers (computed ONCE; incremented per tile; no clamps —
    // t=16 over-reads stay inside ws/finite-bf16 memory and kv>1024 cols are masked)
    const int rowK = wid * 16 + (lane >> 4);
    const int cbsE = ((lane & 15) * 16) ^ ((rowK & 7) << 4);
    const u16* kpe = kbase + (size_t)rowK * C_ + (cbsE >> 1);
    const u16* kpo = kbase + (size_t)(rowK + 4) * C_ + ((cbsE ^ 64) >> 1);
    const int rowV = wid * 32 + (lane >> 3);
    const int cbsV = ((lane & 7) * 16) ^ ((rowV & 7) << 4);
    const u16* vp = vbase + (size_t)rowV * NPAD_ + (cbsV >> 1);

    const bf16x8 ones = {0x3F80, 0x3F80, 0x3F80, 0x3F80, 0x3F80, 0x3F80, 0x3F80, 0x3F80};
    float mrow[4];
    const f32x4 FZ = {0.f, 0.f, 0.f, 0.f};
    f32x4 of[8], lsacc = FZ;
#pragma unroll
    for (int r = 0; r < 4; ++r) mrow[r] = -3e38f;
#pragma unroll
    for (int ct = 0; ct < 8; ++ct) of[ct] = FZ;

    char* psb = (char*)Ps + wid * 2048;

    for (int t = 0; t < 17; ++t) {
        __syncthreads();                     // prev tile's LDS reads done
        gload16(kpe,              Ks + (wid * 4 + 0) * 512);
        gload16(kpo,              Ks + (wid * 4 + 1) * 512);
        gload16(kpe + 8 * C_,     Ks + (wid * 4 + 2) * 512);
        gload16(kpo + 8 * C_,     Ks + (wid * 4 + 3) * 512);
        gload16(vp,               Vs + (wid * 4 + 0) * 512);
        gload16(vp + 8 * NPAD_,   Vs + (wid * 4 + 1) * 512);
        gload16(vp + 16 * NPAD_,  Vs + (wid * 4 + 2) * 512);
        gload16(vp + 24 * NPAD_,  Vs + (wid * 4 + 3) * 512);
        kpe += 64 * C_; kpo += 64 * C_; vp += 64;
        __syncthreads();                     // loads landed (compiler drains vmcnt)

        f32x4 s[4];
        __builtin_amdgcn_s_setprio(1);
#pragma unroll
        for (int jt = 0; jt < 4; ++jt) {
            f32x4 a = FZ;
#pragma unroll
            for (int ks = 0; ks < 4; ++ks) {
                int kvr = jt * 16 + (lane & 15);
                int byte = (kvr * 256 + ks * 64 + (lane >> 4) * 16) ^ ((kvr & 7) << 4);
                bf16x8 kf = *(const bf16x8*)((const char*)Ks + byte);
                a = __builtin_amdgcn_mfma_f32_16x16x32_bf16(qf[ks], kf, a, 0, 0, 0);
            }
            s[jt] = a;                       // already log2-scaled (folded into q)
        }
        __builtin_amdgcn_s_setprio(0);
        if (t == 16) {                       // only the last tile has kv > 1024
#pragma unroll
            for (int jt = 0; jt < 4; ++jt) {
                int kvglob = 1024 + jt * 16 + (lane & 15);
                if (kvglob > 1024) {
                    s[jt][0] = -3e38f; s[jt][1] = -3e38f;
                    s[jt][2] = -3e38f; s[jt][3] = -3e38f;
                }
            }
        }

        // fast check: packed group max (4 rows folded), 4 shuffles total
        float rmax[4];
#pragma unroll
        for (int r = 0; r < 4; ++r)
            rmax[r] = fmaxf(fmaxf(s[0][r], s[1][r]), fmaxf(s[2][r], s[3][r]));
        float g = fmaxf(fmaxf(rmax[0], rmax[1]), fmaxf(rmax[2], rmax[3]));
#pragma unroll
        for (int off = 1; off < 16; off <<= 1) g = fmaxf(g, __shfl_xor(g, off));
        int need = 0;
#pragma unroll
        for (int r = 0; r < 4; ++r) need |= (g > mrow[r] + THR) ? 1 : 0;

        if (__any(need)) {                   // rare: exact per-row max + rescale
            float al[4];
#pragma unroll
            for (int r = 0; r < 4; ++r) {
                float t0 = rmax[r];
#pragma unroll
                for (int off = 1; off < 16; off <<= 1) t0 = fmaxf(t0, __shfl_xor(t0, off));
                float mn = fmaxf(mrow[r], t0);
                al[r] = exp2f(mrow[r] - mn);
                mrow[r] = mn;
            }
#pragma unroll
            for (int ct = 0; ct < 8; ++ct)
#pragma unroll
                for (int r = 0; r < 4; ++r) of[ct][r] *= al[r];
#pragma unroll
            for (int r = 0; r < 4; ++r) lsacc[r] *= al[r];
        }
#pragma unroll
        for (int jt = 0; jt < 4; ++jt)
#pragma unroll
            for (int r = 0; r < 4; ++r) s[jt][r] = exp2f(s[jt][r] - mrow[r]);

        // P -> LDS via cvt_pk; Ps is wave-private (no barrier needed)
#pragma unroll
        for (int jt = 0; jt < 4; ++jt) {
            unsigned pk01 = cvt_pk_bf16(s[jt][0], s[jt][1]);
            unsigned pk23 = cvt_pk_bf16(s[jt][2], s[jt][3]);
            int colb = (jt * 16 + (lane & 15)) * 2;
            int pr0 = (lane >> 4) * 4;
            *(u16*)(psb + psw(pr0,     colb)) = (u16)pk01;
            *(u16*)(psb + psw(pr0 + 1, colb)) = (u16)(pk01 >> 16);
            *(u16*)(psb + psw(pr0 + 2, colb)) = (u16)pk23;
            *(u16*)(psb + psw(pr0 + 3, colb)) = (u16)(pk23 >> 16);
        }

        bf16x8 pa[2];
#pragma unroll
        for (int ks2 = 0; ks2 < 2; ++ks2) {
            int prr = lane & 15;
            pa[ks2] = *(const bf16x8*)(psb + psw(prr, ks2 * 64 + (lane >> 4) * 16));
        }

        __builtin_amdgcn_s_setprio(1);
        lsacc = __builtin_amdgcn_mfma_f32_16x16x32_bf16(pa[0], ones, lsacc, 0, 0, 0);
        lsacc = __builtin_amdgcn_mfma_f32_16x16x32_bf16(pa[1], ones, lsacc, 0, 0, 0);
#pragma unroll
        for (int ct = 0; ct < 8; ++ct)
#pragma unroll
            for (int ks2 = 0; ks2 < 2; ++ks2) {
                int d = ct * 16 + (lane & 15);
                int byte = (d * 128 + ks2 * 64 + (lane >> 4) * 16) ^ ((d & 7) << 4);
                bf16x8 vf = *(const bf16x8*)((const char*)Vs + byte);
                of[ct] = __builtin_amdgcn_mfma_f32_16x16x32_bf16(pa[ks2], vf, of[ct], 0, 0, 0);
            }
        __builtin_amdgcn_s_setprio(0);
    }

#pragma unroll
    for (int ct = 0; ct < 8; ++ct)
#pragma unroll
        for (int r = 0; r < 4; ++r) {
            int n = n0q + wid * 16 + (lane >> 4) * 4 + r;   // <= 1023
            ob[(size_t)(b * N_ + n) * C_ + h * D_ + ct * 16 + (lane & 15)] =
                f2bf(of[ct][r] / lsacc[r]);
        }
}

// ---------------- cls-row attention (q = row 1024 per (b,h)): 64 blocks x 128 thr ------
__global__ __launch_bounds__(128) void attn_cls(
    const u16* __restrict__ qb, const u16* __restrict__ kkb,
    const u16* __restrict__ vvT, u16* __restrict__ ob)
{
    __shared__ float sl[1025];
    __shared__ float red[2];
    const int tid = threadIdx.x;
    const int bh = blockIdx.x, b = bh >> 3, h = bh & 7;

    // q row (already log2-domain scaled)
    bf16x8 q[16];
    const u16* qp = qb + (size_t)(b * N_ + 1024) * C_ + h * D_;
#pragma unroll
    for (int s = 0; s < 16; ++s) q[s] = *(const bf16x8*)(qp + s * 8);

    // scores s_j = q . K_j
    for (int j = tid; j < 1025; j += 128) {
        const u16* kp = kkb + (size_t)(b * N_ + j) * C_ + h * D_;
        float acc = 0.f;
#pragma unroll
        for (int s2 = 0; s2 < 16; ++s2) {
            bf16x8 kv8 = *(const bf16x8*)(kp + s2 * 8);
#pragma unroll
            for (int e = 0; e < 8; ++e) acc += bf2f(q[s2][e]) * bf2f(kv8[e]);
        }
        sl[j] = acc;
    }
    __syncthreads();

    // block max
    float m = -3e38f;
    for (int j = tid; j < 1025; j += 128) m = fmaxf(m, sl[j]);
#pragma unroll
    for (int off = 1; off < 64; off <<= 1) m = fmaxf(m, __shfl_xor(m, off));
    if ((tid & 63) == 0) red[tid >> 6] = m;
    __syncthreads();
    m = fmaxf(red[0], red[1]);
    __syncthreads();

    // p_j and sum
    float ps = 0.f;
    for (int j = tid; j < 1025; j += 128) { float p = exp2f(sl[j] - m); sl[j] = p; ps += p; }
#pragma unroll
    for (int off = 1; off < 64; off <<= 1) ps += __shfl_xor(ps, off);
    if ((tid & 63) == 0) red[tid >> 6] = ps;
    __syncthreads();
    float lsum = red[0] + red[1];
    __syncthreads();

    // O_d = sum_j p_j * V[j][d]  (thread = d, streams vvT row d)
    const u16* vp = vvT + ((size_t)bh * D_ + tid) * NPAD_;
    float o = 0.f;
    for (int j0 = 0; j0 < 1025; j0 += 8) {
        bf16x8 v8 = *(const bf16x8*)(vp + j0);
#pragma unroll
        for (int e = 0; e < 8; ++e) {
            int j = j0 + e;
            if (j < 1025) o += sl[j] * bf2f(v8[e]);
        }
    }
    ob[(size_t)(b * N_ + 1024) * C_ + h * D_ + tid] = f2bf(o / lsum);
}

extern "C" void kernel_launch(void* const* d_in, const int* in_sizes, int n_in,
                              void* d_out, int out_size, void* d_ws, size_t ws_size,
                              hipStream_t stream)
{
    const float* x       = (const float*)d_in[0];
    const float* style_k = (const float*)d_in[1];
    const float* style_v = (const float*)d_in[2];
    const float* W_qkv   = (const float*)d_in[3];
    const float* W_proj  = (const float*)d_in[4];
    const float* b_proj  = (const float*)d_in[5];
    const float* ak      = (const float*)d_in[6];
    const float* bk      = (const float*)d_in[7];
    const float* av      = (const float*)d_in[8];
    const float* bv      = (const float*)d_in[9];
    const float* W1      = (const float*)d_in[10];
    const float* b1      = (const float*)d_in[11];
    const float* W2      = (const float*)d_in[12];
    const float* b2      = (const float*)d_in[13];

    float* outp   = (float*)d_out;
    float* vv_out = outp + (size_t)M_ * C_;        // second tuple output (fp32)

    // scratch parked in d_out x_return region (dead until proj_gemm writes it): ~25.4 MB
    u16* WqkvT = (u16*)outp;                       // 3*1024*1024
    u16* xbb   = WqkvT + (size_t)3072 * 1024;      // M_*C_
    u16* W1T   = xbb + (size_t)M_ * C_;            // 256*1024
    u16* akp   = W1T + (size_t)256 * 1024;         // 1024*32
    u16* avp   = akp + 1024 * 32;                  // 1024*32
    u16* bkb   = avp + 1024 * 32;                  // 16*1024
    u16* bvb   = bkb + 16 * 1024;                  // 16*1024
    u16* sk16p = bvb + 16 * 1024;                  // M_*32
    u16* sv16p = sk16p + (size_t)M_ * 32;          // M_*32 (ends ~25.4MB < 33.55MB)

    // ws layout (u16 units): ~69.4 MB
    u16* ws     = (u16*)d_ws;
    u16* qb     = ws;                              // M_*C_   (xT alias before qkv)
    u16* kkb    = qb  + (size_t)M_ * C_;           // M_*C_
    u16* obuf   = kkb + (size_t)M_ * C_;           // M_*C_   (skb alias before attn)
    u16* vvT    = obuf + (size_t)M_ * C_;          // 64*128*NPAD_ (svb alias before vvt)
    u16* WprojT = vvT + (size_t)B_ * H_ * D_ * NPAD_;
    float* wcls = (float*)(WprojT + (size_t)1024 * 1024);
    float* gred = wcls + 8192;                     // 8192 f32 partials for SE
    u16* skb = obuf;   // lifetime: cast3 .. lora16_mfma
    u16* svb = vvT;    // lifetime: cast3 .. lora16_mfma (vvt overwrites after)
    u16* xT  = qb;     // lifetime: xt .. se_gemm (qkv overwrites after)

    wt_kernel<<<dim3(96, 32), 256, 0, stream>>>(W_qkv, WqkvT, 1024, 3072);
    wt_kernel<<<dim3(32, 32), 256, 0, stream>>>(W_proj, WprojT, 1024, 1024);
    wt_kernel<<<dim3(8, 32), 256, 0, stream>>>(W1, W1T, 1024, 256);
    padcast16_kernel<<<dim3(64, 2), 256, 0, stream>>>(ak, av, akp, avp);
    castb_kernel<<<dim3(64, 2), 256, 0, stream>>>(bk, bv, bkb, bvb);
    cast3_kernel<<<dim3(4100, 3), 256, 0, stream>>>(x, style_k, style_v, xbb, skb, svb);
    xt_kernel<<<dim3(32, 32, 8), 256, 0, stream>>>(x, xT);
    hipMemsetAsync(gred, 0, 8192 * sizeof(float), stream);
    se_gemm<<<dim3(64, 2), 256, 0, stream>>>(xT, W1T, b1, W2, gred);
    se_fin<<<dim3(32), 256, 0, stream>>>(gred, b2, x, wcls);
    lora16_mfma<<<dim3(129, 2), 256, 0, stream>>>(skb, svb, bkb, bvb, sk16p, sv16p);

    qkv_gemm<<<dim3(65 * 12), 512, 0, stream>>>(xbb, WqkvT, sk16p, sv16p, akp, avp,
                                                qb, kkb, vv_out);
    vvt_kernel<<<dim3(33, 4, 64), 256, 0, stream>>>(vv_out, vvT);
    attn_kernel<<<dim3(16 * 64), 256, 0, stream>>>(qb, kkb, vvT, obuf);
    attn_cls<<<dim3(64), 128, 0, stream>>>(qb, kkb, vvT, obuf);
    proj_gemm<<<dim3(65 * 4), 512, 0, stream>>>(obuf, WprojT, b_proj, wcls, outp);
}

// Round 19
// 301.484 us; speedup vs baseline: 1.2510x; 1.2510x over previous
//
#include <hip/hip_runtime.h>
#include <hip/hip_bf16.h>
#include <stdint.h>

#define B_ 8
#define N_ 1025
#define C_ 1024
#define H_ 8
#define D_ 128
#define TOK_ 1024
#define LORA_ 16
#define M_ 8200          // B_*N_
#define NPAD_ 1032       // padded N for vvT rows

using bf16x8 = __attribute__((ext_vector_type(8))) short;
using f32x4  = __attribute__((ext_vector_type(4))) float;
typedef unsigned short u16;

__device__ __forceinline__ u16 f2bf(float f) {
    union { float f; unsigned u; } v; v.f = f;
    unsigned r = v.u + 0x7fffu + ((v.u >> 16) & 1u);   // RNE
    return (u16)(r >> 16);
}
__device__ __forceinline__ float bf2f(short h) {
    union { unsigned u; float f; } v; v.u = ((unsigned)(unsigned short)h) << 16; return v.f;
}

__device__ __forceinline__ unsigned cvt_pk_bf16(float lo, float hi) {
    unsigned r;
    asm("v_cvt_pk_bf16_f32 %0, %1, %2" : "=v"(r) : "v"(lo), "v"(hi));
    return r;
}

__device__ __forceinline__ void gload16(const u16* g, u16* l) {
    __builtin_amdgcn_global_load_lds(
        (const __attribute__((address_space(1))) void*)g,
        (__attribute__((address_space(3))) void*)l, 16, 0, 0);
}

// bijective XCD swizzle (nwg % 8 == 0)
__device__ __forceinline__ int xcd_swz(int bid, int nwg) {
    int cpx = nwg >> 3;
    return (bid & 7) * cpx + (bid >> 3);
}
// general bijective XCD swizzle (m204 form, any nwg)
__device__ __forceinline__ int xcd_swz_g(int bid, int nwg) {
    int q = nwg >> 3, r = nwg & 7;
    int xcd = bid & 7, i = bid >> 3;
    return (xcd < r ? xcd * (q + 1) : r * (q + 1) + (xcd - r) * q) + i;
}

// ---------------- fp32 -> bf16 cast (x, style_k, style_v), 8 elems/thread --------------
__global__ __launch_bounds__(256) void cast3_kernel(
    const float* __restrict__ x, const float* __restrict__ sk, const float* __restrict__ sv,
    u16* __restrict__ xb, u16* __restrict__ skb, u16* __restrict__ svb)
{
    const float* in = blockIdx.y == 0 ? x : (blockIdx.y == 1 ? sk : sv);
    u16* out = blockIdx.y == 0 ? xb : (blockIdx.y == 1 ? skb : svb);
    size_t i = (size_t)blockIdx.x * 256 + threadIdx.x;   // covers M_*C_/8 exactly
    float4 a = *((const float4*)in + i * 2);
    float4 b = *((const float4*)in + i * 2 + 1);
    bf16x8 v;
    v[0] = (short)f2bf(a.x); v[1] = (short)f2bf(a.y);
    v[2] = (short)f2bf(a.z); v[3] = (short)f2bf(a.w);
    v[4] = (short)f2bf(b.x); v[5] = (short)f2bf(b.y);
    v[6] = (short)f2bf(b.z); v[7] = (short)f2bf(b.w);
    *(bf16x8*)(out + i * 8) = v;
}

// ---------------- ak/av (1024x16 f32) -> padded bf16 (1024x32, hi 16 cols = 0) ---------
__global__ __launch_bounds__(256) void padcast16_kernel(
    const float* __restrict__ ak, const float* __restrict__ av,
    u16* __restrict__ akp, u16* __restrict__ avp)
{
    const float* in = blockIdx.y ? av : ak;
    u16* out = blockIdx.y ? avp : akp;
    int i = blockIdx.x * 256 + threadIdx.x;          // over 1024*16
    int t = i >> 4, l = i & 15;
    out[(size_t)t * 32 + l] = f2bf(in[i]);
    out[(size_t)t * 32 + 16 + l] = 0;
}

// ---------------- bk/bv (16x1024 f32) -> bf16 ------------------------------------------
__global__ __launch_bounds__(256) void castb_kernel(
    const float* __restrict__ bk, const float* __restrict__ bv,
    u16* __restrict__ bkb, u16* __restrict__ bvb)
{
    const float* in = blockIdx.y ? bv : bk;
    u16* out = blockIdx.y ? bvb : bkb;
    int i = blockIdx.x * 256 + threadIdx.x;          // over 16*1024
    out[i] = f2bf(in[i]);
}

// ---------------- rank-16 projection via MFMA: op[m][l] = sum_c sb[m][c]*bb[l][c] ------
__global__ __launch_bounds__(256) void lora16_mfma(
    const u16* __restrict__ skb, const u16* __restrict__ svb,
    const u16* __restrict__ bkb, const u16* __restrict__ bvb,
    u16* __restrict__ sk16p, u16* __restrict__ sv16p)
{
    const u16* sb = blockIdx.y ? svb : skb;
    const u16* bb = blockIdx.y ? bvb : bkb;
    u16* op = blockIdx.y ? sv16p : sk16p;
    const int lane = threadIdx.x & 63, wid = threadIdx.x >> 6;
    const int base = blockIdx.x * 64 + wid * 16;
    int ma = base + (lane & 15); if (ma > M_ - 1) ma = M_ - 1;
    const int l = lane & 15;
    const u16* arow = sb + (size_t)ma * C_ + (lane >> 4) * 8;
    const u16* brow = bb + (size_t)l * C_ + (lane >> 4) * 8;
    f32x4 acc = {0.f, 0.f, 0.f, 0.f};
#pragma unroll
    for (int k0 = 0; k0 < C_; k0 += 32) {
        bf16x8 af = *(const bf16x8*)(arow + k0);
        bf16x8 bf = *(const bf16x8*)(brow + k0);
        acc = __builtin_amdgcn_mfma_f32_16x16x32_bf16(af, bf, acc, 0, 0, 0);
    }
#pragma unroll
    for (int r = 0; r < 4; ++r) {
        int m = base + (lane >> 4) * 4 + r; if (m > M_ - 1) m = M_ - 1;
        op[(size_t)m * 32 + l] = f2bf(acc[r]);
        op[(size_t)m * 32 + 16 + l] = 0;
    }
}

// ---------------- weight transpose+cast: in (K x Nw) f32 -> out (Nw x K) bf16 ----------
__global__ __launch_bounds__(256) void wt_kernel(
    const float* __restrict__ in, u16* __restrict__ out, int K, int Nw)
{
    __shared__ float t[32][33];
    int n0 = blockIdx.x * 32, k0 = blockIdx.y * 32;
    int tx = threadIdx.x & 31, ty = threadIdx.x >> 5;
#pragma unroll
    for (int yy = 0; yy < 32; yy += 8)
        t[ty + yy][tx] = in[(size_t)(k0 + ty + yy) * Nw + n0 + tx];
    __syncthreads();
#pragma unroll
    for (int yy = 0; yy < 32; yy += 8)
        out[(size_t)(n0 + ty + yy) * K + k0 + tx] = f2bf(t[tx][ty + yy]);
}

// ---------------- x[b,1+t,c] f32 -> xT bf16 [b*1024+c][t] ------------------------------
__global__ __launch_bounds__(256) void xt_kernel(
    const float* __restrict__ x, u16* __restrict__ xT)
{
    __shared__ float tb[32][33];
    int t0 = blockIdx.x * 32, c0 = blockIdx.y * 32, b = blockIdx.z;
    int tx = threadIdx.x & 31, ty = threadIdx.x >> 5;
#pragma unroll
    for (int yy = 0; yy < 32; yy += 8)
        tb[ty + yy][tx] = x[((size_t)b * N_ + 1 + t0 + ty + yy) * C_ + c0 + tx];
    __syncthreads();
#pragma unroll
    for (int yy = 0; yy < 32; yy += 8)
        xT[((size_t)b * 1024 + c0 + ty + yy) * 1024 + t0 + tx] = f2bf(tb[tx][ty + yy]);
}

// ---------------- vv (f32) -> vvT bf16 [bh*128+d][NPAD_] -------------------------------
__global__ __launch_bounds__(256) void vvt_kernel(
    const float* __restrict__ vv, u16* __restrict__ vvT)
{
    __shared__ float t[32][33];
    int n0 = blockIdx.x * 32, d0 = blockIdx.y * 32, bh = blockIdx.z;
    int b = bh >> 3, h = bh & 7;
    int tx = threadIdx.x & 31, ty = threadIdx.x >> 5;
#pragma unroll
    for (int yy = 0; yy < 32; yy += 8) {
        int n = n0 + ty + yy; if (n > 1024) n = 1024;
        t[ty + yy][tx] = vv[((size_t)(b * N_) + n) * C_ + h * D_ + d0 + tx];
    }
    __syncthreads();
#pragma unroll
    for (int yy = 0; yy < 32; yy += 8) {
        int n = n0 + tx;
        if (n < NPAD_)
            vvT[((size_t)bh * D_ + d0 + ty + yy) * NPAD_ + n] = f2bf(t[tx][ty + yy]);
    }
}

// ---------------- MFMA GEMM core, 256-thr 128x128 (kept for se_gemm) -------------------
__device__ __forceinline__ void stage_tile(
    const u16* __restrict__ base, int row0, int maxrow,
    u16* lds, int k0, int lane, int wid)
{
#pragma unroll
    for (int j = 0; j < 4; ++j) {
        int i = wid * 4 + j;
        int p = i * 1024 + 16 * lane;
        int row = p >> 7, cb = p & 127;
        int cbs = cb ^ ((row & 7) << 4);
        int gr = row0 + row; if (gr > maxrow) gr = maxrow;
        gload16(base + (size_t)gr * 1024 + k0 + (cbs >> 1), lds + i * 512);
    }
}

__device__ __forceinline__ void gemm_pass(
    const u16* __restrict__ A, const u16* __restrict__ Bt, int row0, int nb0,
    u16* As, u16* Bs, f32x4 acc[4][4],
    const int lane, const int wid, const int wr, const int wc)
{
    for (int k0 = 0; k0 < 1024; k0 += 64) {
        __syncthreads();
        stage_tile(A,  row0, M_ - 1,    As, k0, lane, wid);
        stage_tile(Bt, nb0,  (1 << 30), Bs, k0, lane, wid);
        __syncthreads();
#pragma unroll
        for (int ks = 0; ks < 2; ++ks) {
            bf16x8 af[4], bfr[4];
#pragma unroll
            for (int mi = 0; mi < 4; ++mi) {
                int r = wr * 64 + mi * 16 + (lane & 15);
                int byte = (r * 128 + ks * 64 + (lane >> 4) * 16) ^ ((r & 7) << 4);
                af[mi] = *(const bf16x8*)((const char*)As + byte);
            }
#pragma unroll
            for (int ni = 0; ni < 4; ++ni) {
                int r = wc * 64 + ni * 16 + (lane & 15);
                int byte = (r * 128 + ks * 64 + (lane >> 4) * 16) ^ ((r & 7) << 4);
                bfr[ni] = *(const bf16x8*)((const char*)Bs + byte);
            }
#pragma unroll
            for (int mi = 0; mi < 4; ++mi)
#pragma unroll
                for (int ni = 0; ni < 4; ++ni)
                    acc[mi][ni] = __builtin_amdgcn_mfma_f32_16x16x32_bf16(
                        af[mi], bfr[ni], acc[mi][ni], 0, 0, 0);
        }
    }
}

// ---------------- MFMA GEMM core, 512-thr 128x256 (halved A-refetch) -------------------
template<int NSEG>
__device__ __forceinline__ void stage_tile512(
    const u16* __restrict__ base, int row0, int maxrow,
    u16* lds, int k0, int lane, int wid)
{
#pragma unroll
    for (int j = 0; j < NSEG; ++j) {
        int i = wid * NSEG + j;
        int p = i * 1024 + 16 * lane;
        int row = p >> 7, cb = p & 127;
        int cbs = cb ^ ((row & 7) << 4);
        int gr = row0 + row; if (gr > maxrow) gr = maxrow;
        gload16(base + (size_t)gr * 1024 + k0 + (cbs >> 1), lds + i * 512);
    }
}

__device__ __forceinline__ void gemm_pass512(
    const u16* __restrict__ A, const u16* __restrict__ Bt, int row0, int nb0,
    u16* As, u16* Bs, f32x4 acc[4][4],
    const int lane, const int wid, const int wr, const int wc)
{
    for (int k0 = 0; k0 < 1024; k0 += 64) {
        __syncthreads();
        stage_tile512<2>(A,  row0, M_ - 1,    As, k0, lane, wid);   // 128 rows
        stage_tile512<4>(Bt, nb0,  (1 << 30), Bs, k0, lane, wid);   // 256 rows
        __syncthreads();
#pragma unroll
        for (int ks = 0; ks < 2; ++ks) {
            bf16x8 af[4], bfr[4];
#pragma unroll
            for (int mi = 0; mi < 4; ++mi) {
                int r = wr * 64 + mi * 16 + (lane & 15);
                int byte = (r * 128 + ks * 64 + (lane >> 4) * 16) ^ ((r & 7) << 4);
                af[mi] = *(const bf16x8*)((const char*)As + byte);
            }
#pragma unroll
            for (int ni = 0; ni < 4; ++ni) {
                int r = wc * 64 + ni * 16 + (lane & 15);
                int byte = (r * 128 + ks * 64 + (lane >> 4) * 16) ^ ((r & 7) << 4);
                bfr[ni] = *(const bf16x8*)((const char*)Bs + byte);
            }
#pragma unroll
            for (int mi = 0; mi < 4; ++mi)
#pragma unroll
                for (int ni = 0; ni < 4; ++ni)
                    acc[mi][ni] = __builtin_amdgcn_mfma_f32_16x16x32_bf16(
                        af[mi], bfr[ni], acc[mi][ni], 0, 0, 0);
        }
    }
}

// ---------------- SE module: one j-pass per block, global partials ---------------------
__global__ __launch_bounds__(256) void se_gemm(
    const u16* __restrict__ xT, const u16* __restrict__ W1T,
    const float* __restrict__ b1, const float* __restrict__ W2,
    float* __restrict__ gred)
{
    __shared__ u16 As[8192], Bs[8192];
    __shared__ float red[128];
    const int tid = threadIdx.x, lane = tid & 63, wid = tid >> 6;
    const int wr = wid >> 1, wc = wid & 1;
    const int row0 = blockIdx.x * 128;
    const int pass = blockIdx.y;
    if (tid < 128) red[tid] = 0.f;
    const f32x4 FZ = {0.f, 0.f, 0.f, 0.f};

    f32x4 acc[4][4];
#pragma unroll
    for (int mi = 0; mi < 4; ++mi)
#pragma unroll
        for (int ni = 0; ni < 4; ++ni) acc[mi][ni] = FZ;
    gemm_pass(xT, W1T, row0, pass * 128, As, Bs, acc, lane, wid, wr, wc);
#pragma unroll
    for (int mi = 0; mi < 4; ++mi) {
#pragma unroll
        for (int r = 0; r < 4; ++r) {
            float v = 0.f;
#pragma unroll
            for (int ni = 0; ni < 4; ++ni) {
                int j = pass * 128 + wc * 64 + ni * 16 + (lane & 15);
                float h = acc[mi][ni][r] + b1[j];
                v += fmaxf(h, 0.f) * W2[j];
            }
#pragma unroll
            for (int off = 1; off < 16; off <<= 1) v += __shfl_xor(v, off);
            if ((lane & 15) == 0)
                atomicAdd(&red[wr * 64 + mi * 16 + (lane >> 4) * 4 + r], v);
        }
    }
    __syncthreads();
    if (tid < 128) atomicAdd(&gred[row0 + tid], red[tid]);
}

__global__ __launch_bounds__(256) void se_fin(
    const float* __restrict__ gred, const float* __restrict__ b2,
    const float* __restrict__ x, float* __restrict__ wcls)
{
    int row = blockIdx.x * 256 + threadIdx.x;    // 8192 rows
    int b = row >> 10, c = row & 1023;
    wcls[row] = x[(size_t)b * N_ * C_ + c] / (1.f + expf(-(gred[row] + b2[0])));
}

// ---------------- fused qkv GEMM (512 thr, 128x256): q / kk / vv + rank-16 LoRA --------
__global__ __launch_bounds__(512) void qkv_gemm(
    const u16* __restrict__ xb, const u16* __restrict__ WqkvT,
    const u16* __restrict__ sk16p, const u16* __restrict__ sv16p,
    const u16* __restrict__ akp, const u16* __restrict__ avp,
    u16* __restrict__ qb, u16* __restrict__ kkb, float* __restrict__ vvout)
{
    __shared__ u16 As[8192], Bs[16384];
    const int tid = threadIdx.x, lane = tid & 63, wid = tid >> 6;
    const int wr = wid >> 2, wc = wid & 3;
    const int swz = xcd_swz_g(blockIdx.x, 65 * 12);
    const int row0 = (swz / 12) * 128;          // A-locality: ct fastest
    const int ct = swz % 12, region = ct >> 2;
    const int creg = (ct & 3) * 256;            // column base within region
    const f32x4 FZ = {0.f, 0.f, 0.f, 0.f};
    f32x4 acc[4][4];
#pragma unroll
    for (int mi = 0; mi < 4; ++mi)
#pragma unroll
        for (int ni = 0; ni < 4; ++ni) acc[mi][ni] = FZ;

    gemm_pass512(xb, WqkvT, row0, region * 1024 + creg, As, Bs, acc, lane, wid, wr, wc);

    if (region >= 1) {
        const u16* a16 = (region == 1) ? sk16p : sv16p;
        const u16* b16 = (region == 1) ? akp : avp;
        bf16x8 af2[4], bf2v[4];
#pragma unroll
        for (int mi = 0; mi < 4; ++mi) {
            int gr = row0 + wr * 64 + mi * 16 + (lane & 15);
            if (gr > M_ - 1) gr = M_ - 1;
            af2[mi] = *(const bf16x8*)(a16 + (size_t)gr * 32 + (lane >> 4) * 8);
        }
#pragma unroll
        for (int ni = 0; ni < 4; ++ni) {
            int gc = creg + wc * 64 + ni * 16 + (lane & 15);
            bf2v[ni] = *(const bf16x8*)(b16 + (size_t)gc * 32 + (lane >> 4) * 8);
        }
#pragma unroll
        for (int mi = 0; mi < 4; ++mi)
#pragma unroll
            for (int ni = 0; ni < 4; ++ni)
                acc[mi][ni] = __builtin_amdgcn_mfma_f32_16x16x32_bf16(
                    af2[mi], bf2v[ni], acc[mi][ni], 0, 0, 0);
    }

    const float QSCALE = 0.1275006182f;   // (1/sqrt(128))*log2(e), folded into q
#pragma unroll
    for (int mi = 0; mi < 4; ++mi) {
#pragma unroll
        for (int r = 0; r < 4; ++r) {
            int gr = row0 + wr * 64 + mi * 16 + (lane >> 4) * 4 + r;
            if (gr >= M_) continue;
#pragma unroll
            for (int ni = 0; ni < 4; ++ni) {
                int gc = creg + wc * 64 + ni * 16 + (lane & 15);
                float v = acc[mi][ni][r];
                if (region == 0)      qb [(size_t)gr * C_ + gc] = f2bf(v * QSCALE);
                else if (region == 1) kkb[(size_t)gr * C_ + gc] = f2bf(v);
                else                  vvout[(size_t)gr * C_ + gc] = v;
            }
        }
    }
}

// ---------------- proj GEMM (512 thr, 128x256) -----------------------------------------
__global__ __launch_bounds__(512) void proj_gemm(
    const u16* __restrict__ ob, const u16* __restrict__ WprojT,
    const float* __restrict__ bias, const float* __restrict__ wcls,
    float* __restrict__ outp)
{
    __shared__ u16 As[8192], Bs[16384];
    const int tid = threadIdx.x, lane = tid & 63, wid = tid >> 6;
    const int wr = wid >> 2, wc = wid & 3;
    const int swz = xcd_swz_g(blockIdx.x, 65 * 4);
    const int row0 = (swz / 4) * 128;
    const int ct = swz % 4;
    const f32x4 FZ = {0.f, 0.f, 0.f, 0.f};
    f32x4 acc[4][4];
#pragma unroll
    for (int mi = 0; mi < 4; ++mi)
#pragma unroll
        for (int ni = 0; ni < 4; ++ni) acc[mi][ni] = FZ;

    gemm_pass512(ob, WprojT, row0, ct * 256, As, Bs, acc, lane, wid, wr, wc);

#pragma unroll
    for (int mi = 0; mi < 4; ++mi) {
#pragma unroll
        for (int r = 0; r < 4; ++r) {
            int gr = row0 + wr * 64 + mi * 16 + (lane >> 4) * 4 + r;
            if (gr >= M_) continue;
#pragma unroll
            for (int ni = 0; ni < 4; ++ni) {
                int gc = ct * 256 + wc * 64 + ni * 16 + (lane & 15);
                float v = acc[mi][ni][r] + bias[gc];
                if (gr % N_ == 0) v += wcls[(gr / N_) * C_ + gc];
                outp[(size_t)gr * C_ + gc] = v;
            }
        }
    }
}

// ---------------- flash attention main: rows 0..1023, grid 16x64 = 1024 (no tail) ------
__device__ __forceinline__ int psw(int pr, int colb) {
    return (pr * 128 + colb) ^ ((pr & 7) << 4) ^ ((pr & 8) << 2);
}

__global__ __launch_bounds__(256) void attn_kernel(
    const u16* __restrict__ qb, const u16* __restrict__ kkb,
    const u16* __restrict__ vvT, u16* __restrict__ ob)
{
    __shared__ u16 Ks[8192];   // 16 KB
    __shared__ u16 Vs[8192];   // 16 KB
    __shared__ u16 Ps[4096];   // 8 KB  (per-wave 2KB, wave-private)
    const int tid = threadIdx.x, lane = tid & 63, wid = tid >> 6;
    const int swz = xcd_swz(blockIdx.x, 16 * 64);
    const int qt = swz % 16, bh = swz / 16, b = bh >> 3, h = bh & 7;
    const int n0q = qt * 64;
    const float THR = 11.54f;         // 8 nats in bits (scores already log2-scaled via q)
    const u16* kbase = kkb + (size_t)b * N_ * C_ + h * D_;
    const u16* vbase = vvT + (size_t)bh * D_ * NPAD_;

    bf16x8 qf[4];
    {
        int qrow = n0q + wid * 16 + (lane & 15);            // <= 1023 always
        const u16* qbase = qb + (size_t)(b * N_ + qrow) * C_ + h * D_ + (lane >> 4) * 8;
#pragma unroll
        for (int ks = 0; ks < 4; ++ks) qf[ks] = *(const bf16x8*)(qbase + ks * 32);
    }

    const int rowK = wid * 16 + (lane >> 4);
    const int cbsE = ((lane & 15) * 16) ^ ((rowK & 7) << 4);
    const u16* kpe = kbase + (size_t)rowK * C_ + (cbsE >> 1);
    const u16* kpo = kbase + (size_t)(rowK + 4) * C_ + ((cbsE ^ 64) >> 1);
    const int rowV = wid * 32 + (lane >> 3);
    const int cbsV = ((lane & 7) * 16) ^ ((rowV & 7) << 4);
    const u16* vp = vbase + (size_t)rowV * NPAD_ + (cbsV >> 1);

    const bf16x8 ones = {0x3F80, 0x3F80, 0x3F80, 0x3F80, 0x3F80, 0x3F80, 0x3F80, 0x3F80};
    float mrow[4];
    const f32x4 FZ = {0.f, 0.f, 0.f, 0.f};
    f32x4 of[8], lsacc = FZ;
#pragma unroll
    for (int r = 0; r < 4; ++r) mrow[r] = -3e38f;
#pragma unroll
    for (int ct = 0; ct < 8; ++ct) of[ct] = FZ;

    char* psb = (char*)Ps + wid * 2048;

    for (int t = 0; t < 17; ++t) {
        __syncthreads();                     // prev tile's LDS reads done
        gload16(kpe,              Ks + (wid * 4 + 0) * 512);
        gload16(kpo,              Ks + (wid * 4 + 1) * 512);
        gload16(kpe + 8 * C_,     Ks + (wid * 4 + 2) * 512);
        gload16(kpo + 8 * C_,     Ks + (wid * 4 + 3) * 512);
        gload16(vp,               Vs + (wid * 4 + 0) * 512);
        gload16(vp + 8 * NPAD_,   Vs + (wid * 4 + 1) * 512);
        gload16(vp + 16 * NPAD_,  Vs + (wid * 4 + 2) * 512);
        gload16(vp + 24 * NPAD_,  Vs + (wid * 4 + 3) * 512);
        kpe += 64 * C_; kpo += 64 * C_; vp += 64;
        __syncthreads();                     // loads landed (compiler drains vmcnt)

        f32x4 s[4];
        __builtin_amdgcn_s_setprio(1);
#pragma unroll
        for (int jt = 0; jt < 4; ++jt) {
            f32x4 a = FZ;
#pragma unroll
            for (int ks = 0; ks < 4; ++ks) {
                int kvr = jt * 16 + (lane & 15);
                int byte = (kvr * 256 + ks * 64 + (lane >> 4) * 16) ^ ((kvr & 7) << 4);
                bf16x8 kf = *(const bf16x8*)((const char*)Ks + byte);
                a = __builtin_amdgcn_mfma_f32_16x16x32_bf16(qf[ks], kf, a, 0, 0, 0);
            }
            s[jt] = a;                       // already log2-scaled (folded into q)
        }
        __builtin_amdgcn_s_setprio(0);
        if (t == 16) {                       // only the last tile has kv > 1024
#pragma unroll
            for (int jt = 0; jt < 4; ++jt) {
                int kvglob = 1024 + jt * 16 + (lane & 15);
                if (kvglob > 1024) {
                    s[jt][0] = -3e38f; s[jt][1] = -3e38f;
                    s[jt][2] = -3e38f; s[jt][3] = -3e38f;
                }
            }
        }

        float rmax[4];
#pragma unroll
        for (int r = 0; r < 4; ++r)
            rmax[r] = fmaxf(fmaxf(s[0][r], s[1][r]), fmaxf(s[2][r], s[3][r]));
        float g = fmaxf(fmaxf(rmax[0], rmax[1]), fmaxf(rmax[2], rmax[3]));
#pragma unroll
        for (int off = 1; off < 16; off <<= 1) g = fmaxf(g, __shfl_xor(g, off));
        int need = 0;
#pragma unroll
        for (int r = 0; r < 4; ++r) need |= (g > mrow[r] + THR) ? 1 : 0;

        if (__any(need)) {                   // rare: exact per-row max + rescale
            float al[4];
#pragma unroll
            for (int r = 0; r < 4; ++r) {
                float t0 = rmax[r];
#pragma unroll
                for (int off = 1; off < 16; off <<= 1) t0 = fmaxf(t0, __shfl_xor(t0, off));
                float mn = fmaxf(mrow[r], t0);
                al[r] = exp2f(mrow[r] - mn);
                mrow[r] = mn;
            }
#pragma unroll
            for (int ct = 0; ct < 8; ++ct)
#pragma unroll
                for (int r = 0; r < 4; ++r) of[ct][r] *= al[r];
#pragma unroll
            for (int r = 0; r < 4; ++r) lsacc[r] *= al[r];
        }
#pragma unroll
        for (int jt = 0; jt < 4; ++jt)
#pragma unroll
            for (int r = 0; r < 4; ++r) s[jt][r] = exp2f(s[jt][r] - mrow[r]);

#pragma unroll
        for (int jt = 0; jt < 4; ++jt) {
            unsigned pk01 = cvt_pk_bf16(s[jt][0], s[jt][1]);
            unsigned pk23 = cvt_pk_bf16(s[jt][2], s[jt][3]);
            int colb = (jt * 16 + (lane & 15)) * 2;
            int pr0 = (lane >> 4) * 4;
            *(u16*)(psb + psw(pr0,     colb)) = (u16)pk01;
            *(u16*)(psb + psw(pr0 + 1, colb)) = (u16)(pk01 >> 16);
            *(u16*)(psb + psw(pr0 + 2, colb)) = (u16)pk23;
            *(u16*)(psb + psw(pr0 + 3, colb)) = (u16)(pk23 >> 16);
        }

        bf16x8 pa[2];
#pragma unroll
        for (int ks2 = 0; ks2 < 2; ++ks2) {
            int prr = lane & 15;
            pa[ks2] = *(const bf16x8*)(psb + psw(prr, ks2 * 64 + (lane >> 4) * 16));
        }

        __builtin_amdgcn_s_setprio(1);
        lsacc = __builtin_amdgcn_mfma_f32_16x16x32_bf16(pa[0], ones, lsacc, 0, 0, 0);
        lsacc = __builtin_amdgcn_mfma_f32_16x16x32_bf16(pa[1], ones, lsacc, 0, 0, 0);
#pragma unroll
        for (int ct = 0; ct < 8; ++ct)
#pragma unroll
            for (int ks2 = 0; ks2 < 2; ++ks2) {
                int d = ct * 16 + (lane & 15);
                int byte = (d * 128 + ks2 * 64 + (lane >> 4) * 16) ^ ((d & 7) << 4);
                bf16x8 vf = *(const bf16x8*)((const char*)Vs + byte);
                of[ct] = __builtin_amdgcn_mfma_f32_16x16x32_bf16(pa[ks2], vf, of[ct], 0, 0, 0);
            }
        __builtin_amdgcn_s_setprio(0);
    }

#pragma unroll
    for (int ct = 0; ct < 8; ++ct)
#pragma unroll
        for (int r = 0; r < 4; ++r) {
            int n = n0q + wid * 16 + (lane >> 4) * 4 + r;   // <= 1023
            ob[(size_t)(b * N_ + n) * C_ + h * D_ + ct * 16 + (lane & 15)] =
                f2bf(of[ct][r] / lsacc[r]);
        }
}

// ---------------- cls-row attention, parallel: grid 64x9 = 576 blocks ------------------
// block = (bh, 128-kv chunk). Phase1: thread=j: p=exp2(s) (no max; log2-domain scores are
// small), LDS + atomic lsum. Phase2: thread=d: partial O over chunk, atomic accumulate.
__global__ __launch_bounds__(128) void cls_merged(
    const u16* __restrict__ qb, const u16* __restrict__ kkb,
    const u16* __restrict__ vvT, float* __restrict__ oacc, float* __restrict__ gsum)
{
    __shared__ float sl[128];
    const int tid = threadIdx.x;
    const int bid = blockIdx.x;              // 64*9
    const int bh = bid / 9, chunk = bid - bh * 9;
    const int b = bh >> 3, h = bh & 7;
    const int j = chunk * 128 + tid;

    float p = 0.f;
    if (j < 1025) {
        const u16* qp = qb + (size_t)(b * N_ + 1024) * C_ + h * D_;
        const u16* kp = kkb + (size_t)(b * N_ + j) * C_ + h * D_;
        float acc = 0.f;
#pragma unroll
        for (int s2 = 0; s2 < 16; ++s2) {
            bf16x8 q8 = *(const bf16x8*)(qp + s2 * 8);
            bf16x8 k8 = *(const bf16x8*)(kp + s2 * 8);
#pragma unroll
            for (int e = 0; e < 8; ++e) acc += bf2f(q8[e]) * bf2f(k8[e]);
        }
        p = exp2f(acc);
    }
    sl[tid] = p;
    float bs = p;
#pragma unroll
    for (int off = 1; off < 64; off <<= 1) bs += __shfl_xor(bs, off);
    __syncthreads();                         // sl complete
    if ((tid & 63) == 0) atomicAdd(&gsum[bh], bs);

    // phase 2: thread = d, partial O over this chunk
    float o = 0.f;
    if (chunk < 8) {
        const u16* vp = vvT + ((size_t)bh * D_ + tid) * NPAD_ + chunk * 128;
#pragma unroll
        for (int j0 = 0; j0 < 128; j0 += 8) {
            bf16x8 v8 = *(const bf16x8*)(vp + j0);
#pragma unroll
            for (int e = 0; e < 8; ++e) o += sl[j0 + e] * bf2f(v8[e]);
        }
    } else {
        o = sl[0] * bf2f(*(vvT + ((size_t)bh * D_ + tid) * NPAD_ + 1024));
    }
    atomicAdd(&oacc[bh * 128 + tid], o);
}

__global__ __launch_bounds__(256) void cls_fin(
    const float* __restrict__ oacc, const float* __restrict__ gsum,
    u16* __restrict__ ob)
{
    int idx = blockIdx.x * 256 + threadIdx.x;    // 8192
    int bh = idx >> 7, d = idx & 127;
    int b = bh >> 3, h = bh & 7;
    ob[(size_t)(b * N_ + 1024) * C_ + h * D_ + d] = f2bf(oacc[idx] / gsum[bh]);
}

extern "C" void kernel_launch(void* const* d_in, const int* in_sizes, int n_in,
                              void* d_out, int out_size, void* d_ws, size_t ws_size,
                              hipStream_t stream)
{
    const float* x       = (const float*)d_in[0];
    const float* style_k = (const float*)d_in[1];
    const float* style_v = (const float*)d_in[2];
    const float* W_qkv   = (const float*)d_in[3];
    const float* W_proj  = (const float*)d_in[4];
    const float* b_proj  = (const float*)d_in[5];
    const float* ak      = (const float*)d_in[6];
    const float* bk      = (const float*)d_in[7];
    const float* av      = (const float*)d_in[8];
    const float* bv      = (const float*)d_in[9];
    const float* W1      = (const float*)d_in[10];
    const float* b1      = (const float*)d_in[11];
    const float* W2      = (const float*)d_in[12];
    const float* b2      = (const float*)d_in[13];

    float* outp   = (float*)d_out;
    float* vv_out = outp + (size_t)M_ * C_;        // second tuple output (fp32)

    // scratch parked in d_out x_return region (dead until proj_gemm writes it): ~25.4 MB
    u16* WqkvT = (u16*)outp;                       // 3*1024*1024
    u16* xbb   = WqkvT + (size_t)3072 * 1024;      // M_*C_
    u16* W1T   = xbb + (size_t)M_ * C_;            // 256*1024
    u16* akp   = W1T + (size_t)256 * 1024;         // 1024*32
    u16* avp   = akp + 1024 * 32;                  // 1024*32
    u16* bkb   = avp + 1024 * 32;                  // 16*1024
    u16* bvb   = bkb + 16 * 1024;                  // 16*1024
    u16* sk16p = bvb + 16 * 1024;                  // M_*32
    u16* sv16p = sk16p + (size_t)M_ * 32;          // M_*32 (ends ~25.4MB < 33.55MB)

    // ws layout (u16 units): ~69.5 MB
    u16* ws     = (u16*)d_ws;
    u16* qb     = ws;                              // M_*C_   (xT alias before qkv)
    u16* kkb    = qb  + (size_t)M_ * C_;           // M_*C_
    u16* obuf   = kkb + (size_t)M_ * C_;           // M_*C_   (skb alias before attn)
    u16* vvT    = obuf + (size_t)M_ * C_;          // 64*128*NPAD_ (svb alias before vvt)
    u16* WprojT = vvT + (size_t)B_ * H_ * D_ * NPAD_;
    float* wcls = (float*)(WprojT + (size_t)1024 * 1024);
    float* gred = wcls + 8192;                     // 8192 f32 partials for SE
    float* oacc = gred + 8192;                     // 8192 f32 cls O partials
    float* gsum = oacc + 8192;                     // 64 f32 cls lsum
    u16* skb = obuf;   // lifetime: cast3 .. lora16_mfma
    u16* svb = vvT;    // lifetime: cast3 .. lora16_mfma (vvt overwrites after)
    u16* xT  = qb;     // lifetime: xt .. se_gemm (qkv overwrites after)

    wt_kernel<<<dim3(96, 32), 256, 0, stream>>>(W_qkv, WqkvT, 1024, 3072);
    wt_kernel<<<dim3(32, 32), 256, 0, stream>>>(W_proj, WprojT, 1024, 1024);
    wt_kernel<<<dim3(8, 32), 256, 0, stream>>>(W1, W1T, 1024, 256);
    padcast16_kernel<<<dim3(64, 2), 256, 0, stream>>>(ak, av, akp, avp);
    castb_kernel<<<dim3(64, 2), 256, 0, stream>>>(bk, bv, bkb, bvb);
    cast3_kernel<<<dim3(4100, 3), 256, 0, stream>>>(x, style_k, style_v, xbb, skb, svb);
    xt_kernel<<<dim3(32, 32, 8), 256, 0, stream>>>(x, xT);
    hipMemsetAsync(gred, 0, (8192 + 8192 + 64) * sizeof(float), stream);
    se_gemm<<<dim3(64, 2), 256, 0, stream>>>(xT, W1T, b1, W2, gred);
    se_fin<<<dim3(32), 256, 0, stream>>>(gred, b2, x, wcls);
    lora16_mfma<<<dim3(129, 2), 256, 0, stream>>>(skb, svb, bkb, bvb, sk16p, sv16p);

    qkv_gemm<<<dim3(65 * 12), 512, 0, stream>>>(xbb, WqkvT, sk16p, sv16p, akp, avp,
                                                qb, kkb, vv_out);
    vvt_kernel<<<dim3(33, 4, 64), 256, 0, stream>>>(vv_out, vvT);
    cls_merged<<<dim3(64 * 9), 128, 0, stream>>>(qb, kkb, vvT, oacc, gsum);
    attn_kernel<<<dim3(16 * 64), 256, 0, stream>>>(qb, kkb, vvT, obuf);
    cls_fin<<<dim3(32), 256, 0, stream>>>(oacc, gsum, obuf);
    proj_gemm<<<dim3(65 * 4), 512, 0, stream>>>(obuf, WprojT, b_proj, wcls, outp);
}